// Round 8
// baseline (1415.717 us; speedup 1.0000x reference)
//
#include <hip/hip_runtime.h>
#include <stdint.h>

#define H_DIM 1024
#define I_DIM 4096
#define E_NUM 8
#define CAP   1024

typedef __attribute__((ext_vector_type(8))) short bf16x8;
typedef __attribute__((ext_vector_type(4))) float f32x4;

#define AS1 __attribute__((address_space(1)))
#define AS3 __attribute__((address_space(3)))

__device__ __forceinline__ unsigned short f2bf(float f){
  union { float f; uint32_t u; } v; v.f = f;
  uint32_t u = v.u;
  uint32_t r = (u + 0x7FFFu + ((u >> 16) & 1u)) >> 16;
  return (unsigned short)r;
}

// ---------------- zero output ----------------
__global__ void zero_kernel(float4* __restrict__ p, int n4){
  int i = blockIdx.x*blockDim.x + threadIdx.x;
  int stride = gridDim.x*blockDim.x;
  float4 z; z.x=0.f; z.y=0.f; z.z=0.f; z.w=0.f;
  for (; i < n4; i += stride) p[i] = z;
}

// ---------------- router softmax + x -> bf16 (first CAP tokens) ----------------
__global__ __launch_bounds__(256) void router_kernel(
    const float* __restrict__ x, const float* __restrict__ rw_w,
    const float* __restrict__ rb, unsigned short* __restrict__ xb,
    float* __restrict__ rwout)
{
  int c = blockIdx.x;
  int t = threadIdx.x;
  float acc[E_NUM];
  #pragma unroll
  for (int e=0;e<E_NUM;e++) acc[e]=0.f;
  const float* xr = x + (size_t)c*H_DIM;
  for (int h=t; h<H_DIM; h+=256){
    float xv = xr[h];
    xb[(size_t)c*H_DIM + h] = f2bf(xv);
    #pragma unroll
    for (int e=0;e<E_NUM;e++) acc[e] += xv * rw_w[e*H_DIM + h];
  }
  __shared__ float part[256][E_NUM];
  #pragma unroll
  for (int e=0;e<E_NUM;e++) part[t][e]=acc[e];
  __syncthreads();
  for (int s=128; s>0; s>>=1){
    if (t<s){
      #pragma unroll
      for (int e=0;e<E_NUM;e++) part[t][e]+=part[t+s][e];
    }
    __syncthreads();
  }
  if (t==0){
    float l[E_NUM], mx=-1e30f;
    #pragma unroll
    for (int e=0;e<E_NUM;e++){ l[e]=part[0][e]+rb[e]; mx=fmaxf(mx,l[e]); }
    float s=0.f;
    #pragma unroll
    for (int e=0;e<E_NUM;e++){ l[e]=expf(l[e]-mx); s+=l[e]; }
    float inv = 1.f/s;
    #pragma unroll
    for (int e=0;e<E_NUM;e++) rwout[c*E_NUM+e] = l[e]*inv;
  }
}

// ------- fp32 -> bf16 transpose, 64x64 tile, float4 loads / ushort4 stores -------
__global__ __launch_bounds__(256) void transpose_cvt64(
    const float* __restrict__ src, unsigned short* __restrict__ dst,
    int R, int C, long srcZ, long dstZ)
{
  src += (size_t)blockIdx.z * srcZ;
  dst += (size_t)blockIdx.z * dstZ;
  __shared__ float tile[64][65];
  int c0 = blockIdx.x*64, r0 = blockIdx.y*64;
  int t  = threadIdx.x;
  int tx = t & 15, ty = t >> 4;
  #pragma unroll
  for (int p=0;p<4;p++){
    int r = ty + p*16;
    float4 v = *(const float4*)(src + (size_t)(r0+r)*C + c0 + tx*4);
    tile[r][tx*4+0]=v.x; tile[r][tx*4+1]=v.y; tile[r][tx*4+2]=v.z; tile[r][tx*4+3]=v.w;
  }
  __syncthreads();
  #pragma unroll
  for (int p=0;p<4;p++){
    int c = ty + p*16;
    ushort4 o;
    o.x = f2bf(tile[tx*4+0][c]);
    o.y = f2bf(tile[tx*4+1][c]);
    o.z = f2bf(tile[tx*4+2][c]);
    o.w = f2bf(tile[tx*4+3][c]);
    *(ushort4*)(dst + (size_t)(c0+c)*R + r0 + tx*4) = o;
  }
}

// ---- 256x256 bf16 GEMM, B N-major; 2-buffer counted pipeline, 16x16x32 MFMA ----
// 64 KB LDS (2 bufs x 32KB: A[256x32]+B[256x32]) -> 2 blocks/CU (16 waves/CU,
// m114 implicit wave-overlap). Per half: barrierA (frees buf h+1), stage(h+1),
// counted vmcnt(4) (own stage(h) landed, h+1 in flight), barrierB, compute.
// Read swizzle = R2/R3/R5-proven zero-conflict pattern (128B rows,
// slot (kk*4+lq)^(lrow&7)); staging source pre-swizzled, LDS dest linear.
// MODE 0: relu*rw -> bf16 inter.  MODE 1: atomicAdd fp32.
template<int MODE>
__global__ __launch_bounds__(512, 4) void gemm2b(
    const unsigned short* __restrict__ A, int lda, long aZ,
    const unsigned short* __restrict__ B, int ldb, long bZ,
    int NH, int tilesPerZ,
    const float* __restrict__ rw,
    unsigned short* __restrict__ outInter,
    float* __restrict__ outAdd)
{
  extern __shared__ char smem[];   // 65536 = 2 bufs x (A 16KB | B 16KB)

  // T1: XCD-aware swizzle (gridDim.x % 8 == 0)
  int nwg = gridDim.x;
  int id  = blockIdx.x;
  int swz = (id & 7)*(nwg >> 3) + (id >> 3);
  int z   = swz / tilesPerZ;
  int rr_ = swz - z*tilesPerZ;
  int mt  = rr_ & 3, nt = rr_ >> 2;
  int m0  = mt*256, n0 = nt*256;

  const unsigned short* Ab = A + (size_t)z*aZ + (size_t)m0*lda;
  const unsigned short* Bb = B + (size_t)z*bZ + (size_t)n0*ldb;

  int tid  = threadIdx.x;
  int w    = tid >> 6, l = tid & 63;
  int wr   = w >> 2,  wc = w & 3;       // wave grid 2M x 4N, wave out 128x64
  int lrow = l & 15,  lq = l >> 4;

  // read-side swizzle (proven zero-conflict): slot = lq ^ ((row>>1)&3);
  // per-lane constant since frag bases are multiples of 16.
  int rsw = (lq ^ ((lrow>>1)&3)) << 4;          // byte offset of 16B slot

  // staging: wave w covers rows [w*32, w*32+32) of both A and B halves.
  int srow  = (l >> 2);
  int sslot = ((l & 3) ^ ((l >> 3) & 3)) * 8;   // inverse-swizzled source slot
  size_t aOff0 = (size_t)(w*32 + srow)      * lda + sslot;
  size_t aOff1 = (size_t)(w*32 + 16 + srow) * lda + sslot;
  size_t bOff0 = (size_t)(w*32 + srow)      * ldb + sslot;
  size_t bOff1 = (size_t)(w*32 + 16 + srow) * ldb + sslot;
  int ldsA0 = (w*32)*64, ldsA1 = (w*32+16)*64;

  auto stageHalf = [&](int h){
    char* lb = smem + ((h & 1) << 15);
    int kb = h << 5;
    __builtin_amdgcn_global_load_lds((const AS1 void*)(Ab + aOff0 + kb),
        (AS3 void*)(lb + ldsA0), 16, 0, 0);
    __builtin_amdgcn_global_load_lds((const AS1 void*)(Ab + aOff1 + kb),
        (AS3 void*)(lb + ldsA1), 16, 0, 0);
    __builtin_amdgcn_global_load_lds((const AS1 void*)(Bb + bOff0 + kb),
        (AS3 void*)(lb + 16384 + ldsA0), 16, 0, 0);
    __builtin_amdgcn_global_load_lds((const AS1 void*)(Bb + bOff1 + kb),
        (AS3 void*)(lb + 16384 + ldsA1), 16, 0, 0);
  };

  f32x4 acc[8][4];
  #pragma unroll
  for (int i=0;i<8;i++)
    #pragma unroll
    for (int j=0;j<4;j++)
      acc[i][j] = (f32x4){0.f,0.f,0.f,0.f};

  auto compute = [&](int h){
    char* lb = smem + ((h & 1) << 15);
    bf16x8 af[8], bfr[4];
    #pragma unroll
    for (int Mf=0;Mf<8;Mf++)
      af[Mf] = *(const bf16x8*)(lb + (wr*128 + Mf*16 + lrow)*64 + rsw);
    #pragma unroll
    for (int Nf=0;Nf<4;Nf++)
      bfr[Nf] = *(const bf16x8*)(lb + 16384 + (wc*64 + Nf*16 + lrow)*64 + rsw);
    __builtin_amdgcn_s_setprio(1);
    #pragma unroll
    for (int Mf=0;Mf<8;Mf++)
      #pragma unroll
      for (int Nf=0;Nf<4;Nf++)
        acc[Mf][Nf] = __builtin_amdgcn_mfma_f32_16x16x32_bf16(af[Mf], bfr[Nf], acc[Mf][Nf], 0, 0, 0);
    __builtin_amdgcn_s_setprio(0);
  };

  // prologue
  stageHalf(0);

  for (int h = 0; h < NH; ++h){
    __builtin_amdgcn_s_barrier();        // A: all waves done reading buf(h+1)'s slot
    if (h+1 < NH){
      stageHalf(h+1);
      asm volatile("s_waitcnt vmcnt(4)" ::: "memory");   // own stage(h) landed
    } else {
      asm volatile("s_waitcnt vmcnt(0)" ::: "memory");
    }
    __builtin_amdgcn_s_barrier();        // B: buf(h) ready for all waves
    compute(h);
  }

  // epilogue: C/D layout col = lane&15, row = (lane>>4)*4 + reg
  #pragma unroll
  for (int Mf=0;Mf<8;Mf++){
    #pragma unroll
    for (int Nf=0;Nf<4;Nf++){
      #pragma unroll
      for (int rg=0;rg<4;rg++){
        int gm = m0 + wr*128 + Mf*16 + lq*4 + rg;
        int gn = n0 + wc*64 + Nf*16 + lrow;
        float v = acc[Mf][Nf][rg];
        if (MODE==0){
          v = fmaxf(v, 0.f) * rw[gm*E_NUM + z];
          outInter[(size_t)gm*(E_NUM*I_DIM) + (size_t)z*I_DIM + gn] = f2bf(v);
        } else {
          atomicAdd(&outAdd[(size_t)gm*H_DIM + gn], v);
        }
      }
    }
  }
}

extern "C" void kernel_launch(void* const* d_in, const int* in_sizes, int n_in,
                              void* d_out, int out_size, void* d_ws, size_t ws_size,
                              hipStream_t stream)
{
  const float* x   = (const float*)d_in[0];
  const float* rww = (const float*)d_in[1];
  const float* rwb = (const float*)d_in[2];
  const float* w1  = (const float*)d_in[3];  // (E, H, I)
  const float* w2  = (const float*)d_in[4];  // (E, I, H)
  float* out = (float*)d_out;

  char* ws = (char*)d_ws;
  float*          rwout = (float*)(ws);                         // 32 KB
  unsigned short* xb    = (unsigned short*)(ws + (1u<<16));     // 2 MB  @64KB
  unsigned short* inter = (unsigned short*)(ws + (4ull<<20));   // 64 MB @4MB
  unsigned short* wt    = (unsigned short*)(ws + (68ull<<20));  // 64 MB @68MB
  const size_t needed = 132ull<<20;

  zero_kernel<<<2048, 256, 0, stream>>>((float4*)out, out_size/4);
  if (ws_size < needed) return;

  void* k0 = (void*)gemm2b<0>;
  void* k1 = (void*)gemm2b<1>;
  hipFuncSetAttribute(k0, hipFuncAttributeMaxDynamicSharedMemorySize, 65536);
  hipFuncSetAttribute(k1, hipFuncAttributeMaxDynamicSharedMemorySize, 65536);

  router_kernel<<<CAP, 256, 0, stream>>>(x, rww, rwb, xb, rwout);

  // W1 (E,H,I) -> W1^T per expert (I x H) bf16
  transpose_cvt64<<<dim3(I_DIM/64, H_DIM/64, E_NUM), 256, 0, stream>>>(
      w1, wt, H_DIM, I_DIM, (long)H_DIM*I_DIM, (long)I_DIM*H_DIM);

  // GEMM1: inter[c, e*I+n] = bf16( relu( xb @ W1_e^T ) * rw[c,e] )
  // grid 512 = (4 mtiles x 16 ntiles) x 8 experts; K=1024 -> NH=32; 2 blk/CU
  gemm2b<0><<<512, 512, 65536, stream>>>(
      xb, H_DIM, 0L,
      wt, H_DIM, (long)I_DIM*H_DIM,
      32, 64, rwout, inter, nullptr);

  // W2 flat (E*I x H) -> W2^T (H x E*I) bf16
  transpose_cvt64<<<dim3(H_DIM/64, (E_NUM*I_DIM)/64, 1), 256, 0, stream>>>(
      w2, wt, E_NUM*I_DIM, H_DIM, 0L, 0L);

  // GEMM2: out[c,h] += inter[c,:] @ W2^T[h,:]; split-K z=32 slices of 1024 -> NH=32
  // grid 512 = (4 mtiles x 4 ntiles) x 32 z; 2 blk/CU
  gemm2b<1><<<512, 512, 65536, stream>>>(
      inter, E_NUM*I_DIM, 1024L,
      wt,    E_NUM*I_DIM, 1024L,
      32, 16, nullptr, nullptr, out);
}

// Round 9
// 280.917 us; speedup vs baseline: 5.0396x; 5.0396x over previous
//
#include <hip/hip_runtime.h>
#include <stdint.h>

#define H_DIM 1024
#define I_DIM 4096
#define E_NUM 8
#define CAP   1024

typedef __attribute__((ext_vector_type(8))) short bf16x8;
typedef __attribute__((ext_vector_type(4))) float f32x4;

#define AS1 __attribute__((address_space(1)))
#define AS3 __attribute__((address_space(3)))

__device__ __forceinline__ unsigned short f2bf(float f){
  union { float f; uint32_t u; } v; v.f = f;
  uint32_t u = v.u;
  uint32_t r = (u + 0x7FFFu + ((u >> 16) & 1u)) >> 16;
  return (unsigned short)r;
}

// ---------------- zero output ----------------
__global__ void zero_kernel(float4* __restrict__ p, int n4){
  int i = blockIdx.x*blockDim.x + threadIdx.x;
  int stride = gridDim.x*blockDim.x;
  float4 z; z.x=0.f; z.y=0.f; z.z=0.f; z.w=0.f;
  for (; i < n4; i += stride) p[i] = z;
}

// ---------------- router softmax + x -> bf16 (first CAP tokens) ----------------
__global__ __launch_bounds__(256) void router_kernel(
    const float* __restrict__ x, const float* __restrict__ rw_w,
    const float* __restrict__ rb, unsigned short* __restrict__ xb,
    float* __restrict__ rwout)
{
  int c = blockIdx.x;
  int t = threadIdx.x;
  float acc[E_NUM];
  #pragma unroll
  for (int e=0;e<E_NUM;e++) acc[e]=0.f;
  const float* xr = x + (size_t)c*H_DIM;
  for (int h=t; h<H_DIM; h+=256){
    float xv = xr[h];
    xb[(size_t)c*H_DIM + h] = f2bf(xv);
    #pragma unroll
    for (int e=0;e<E_NUM;e++) acc[e] += xv * rw_w[e*H_DIM + h];
  }
  __shared__ float part[256][E_NUM];
  #pragma unroll
  for (int e=0;e<E_NUM;e++) part[t][e]=acc[e];
  __syncthreads();
  for (int s=128; s>0; s>>=1){
    if (t<s){
      #pragma unroll
      for (int e=0;e<E_NUM;e++) part[t][e]+=part[t+s][e];
    }
    __syncthreads();
  }
  if (t==0){
    float l[E_NUM], mx=-1e30f;
    #pragma unroll
    for (int e=0;e<E_NUM;e++){ l[e]=part[0][e]+rb[e]; mx=fmaxf(mx,l[e]); }
    float s=0.f;
    #pragma unroll
    for (int e=0;e<E_NUM;e++){ l[e]=expf(l[e]-mx); s+=l[e]; }
    float inv = 1.f/s;
    #pragma unroll
    for (int e=0;e<E_NUM;e++) rwout[c*E_NUM+e] = l[e]*inv;
  }
}

// ------- fp32 -> bf16 transpose, 64x64 tile, float4 loads / ushort4 stores -------
__global__ __launch_bounds__(256) void transpose_cvt64(
    const float* __restrict__ src, unsigned short* __restrict__ dst,
    int R, int C, long srcZ, long dstZ)
{
  src += (size_t)blockIdx.z * srcZ;
  dst += (size_t)blockIdx.z * dstZ;
  __shared__ float tile[64][65];
  int c0 = blockIdx.x*64, r0 = blockIdx.y*64;
  int t  = threadIdx.x;
  int tx = t & 15, ty = t >> 4;
  #pragma unroll
  for (int p=0;p<4;p++){
    int r = ty + p*16;
    float4 v = *(const float4*)(src + (size_t)(r0+r)*C + c0 + tx*4);
    tile[r][tx*4+0]=v.x; tile[r][tx*4+1]=v.y; tile[r][tx*4+2]=v.z; tile[r][tx*4+3]=v.w;
  }
  __syncthreads();
  #pragma unroll
  for (int p=0;p<4;p++){
    int c = ty + p*16;
    ushort4 o;
    o.x = f2bf(tile[tx*4+0][c]);
    o.y = f2bf(tile[tx*4+1][c]);
    o.z = f2bf(tile[tx*4+2][c]);
    o.w = f2bf(tile[tx*4+3][c]);
    *(ushort4*)(dst + (size_t)(c0+c)*R + r0 + tx*4) = o;
  }
}

// ---- 256x256 bf16 GEMM, B N-major; faithful m201-style 8-phase schedule ----
// BK=64, 8 waves (2M x 4N), wave out = 2 strips of 64 rows x 2 strips of 32 cols.
// LDS 128KB = 2 K-tile bufs x (A: 2x16KB halves + B: 2x16KB halves).
// Half layout: [128 rows][64 elems] bf16, st_16x32 swizzle: byte ^= ((byte>>9)&1)<<5
// (= col granule ^ ((row>>2)&1)<<1). Staging linear-dest global_load_lds with
// inverse-swizzled source column. 4 phases per K-tile, phase (qm,qn) order
// (0,0),(1,0),(1,1),(0,1); each: {ds_reads, stage 1 half-tile, counted vmcnt
// (P0/P1/P3 only), barrier, lgkmcnt(0), setprio, 16 MFMA, setprio, barrier}.
// Stage lag 4 phases; in-flight 2-3 half-tiles; drain only at final K-tile.
// MODE 0: relu*rw -> bf16 inter.  MODE 1: atomicAdd fp32.
template<int MODE>
__global__ __launch_bounds__(512, 2) void gemm8p(
    const unsigned short* __restrict__ A, int lda, long aZ,
    const unsigned short* __restrict__ B, int ldb, long bZ,
    int NT, int tilesPerZ,
    const float* __restrict__ rw,
    unsigned short* __restrict__ outInter,
    float* __restrict__ outAdd)
{
  extern __shared__ char smem[];   // 131072

  // T1: XCD-aware swizzle (gridDim.x % 8 == 0)
  int nwg = gridDim.x;
  int id  = blockIdx.x;
  int swz = (id & 7)*(nwg >> 3) + (id >> 3);
  int z   = swz / tilesPerZ;
  int rr_ = swz - z*tilesPerZ;
  int mt  = rr_ & 3, nt = rr_ >> 2;
  int m0  = mt*256, n0 = nt*256;

  const unsigned short* Ab = A + (size_t)z*aZ + (size_t)m0*lda;
  const unsigned short* Bb = B + (size_t)z*bZ + (size_t)n0*ldb;

  int tid  = threadIdx.x;
  int w    = tid >> 6, l = tid & 63;
  int wr   = w >> 2,  wc = w & 3;       // wave grid 2M x 4N
  int lrow = l & 15,  lq = l >> 4;
  int sw5  = ((l >> 2) & 1) << 5;       // read-side st_16x32 XOR (per-lane const)

  // staging per-lane constants: instr i covers local rows w*16+i*8+(l>>3),
  // dest linear (base + w*2048 + i*1024 + lane*16); source col granule
  // pre-swizzled: g' = (l&7) ^ (((l>>5)&1)<<1), contiguous 16B per lane.
  int rl_s = w*16 + (l >> 3);
  int sg   = ((l & 7) ^ (((l >> 5) & 1) << 1)) * 8;   // element offset in row

  // stage half-tile idx of K-tile t: idx = {0:A-h0, 1:B-h0, 2:A-h1, 3:B-h1}
  auto stageHT = [&](int t, int idx){
    int isB = idx & 1, hh = idx >> 1;
    const unsigned short* src = isB ? Bb : Ab;
    int ld = isB ? ldb : lda;
    char* base = smem + ((t & 1) << 16) + (isB << 15) + (hh << 14);
    __builtin_amdgcn_global_load_lds(
      (const AS1 void*)(src + (size_t)(hh*128 + rl_s)     * ld + t*64 + sg),
      (AS3 void*)(base + w*2048), 16, 0, 0);
    __builtin_amdgcn_global_load_lds(
      (const AS1 void*)(src + (size_t)(hh*128 + rl_s + 8) * ld + t*64 + sg),
      (AS3 void*)(base + w*2048 + 1024), 16, 0, 0);
  };

  f32x4 acc[8][4];
  #pragma unroll
  for (int i=0;i<8;i++)
    #pragma unroll
    for (int j=0;j<4;j++)
      acc[i][j] = (f32x4){0.f,0.f,0.f,0.f};

  bf16x8 af[4][2], bf[2][2];

  auto readA = [&](int t, int qm){
    char* base = smem + ((t & 1) << 16) + (qm << 14);
    #pragma unroll
    for (int Mf=0;Mf<4;Mf++){
      int rowl = wr*64 + Mf*16 + lrow;
      #pragma unroll
      for (int ks=0;ks<2;ks++)
        af[Mf][ks] = *(const bf16x8*)(base + ((rowl*128 + ks*64 + lq*16) ^ sw5));
    }
  };
  auto readB = [&](int t, int qn){
    char* base = smem + ((t & 1) << 16) + 32768 + (qn << 14);
    #pragma unroll
    for (int Nf=0;Nf<2;Nf++){
      int rowl = wc*32 + Nf*16 + lrow;
      #pragma unroll
      for (int ks=0;ks<2;ks++)
        bf[Nf][ks] = *(const bf16x8*)(base + ((rowl*128 + ks*64 + lq*16) ^ sw5));
    }
  };

#define MMA_PHASE(QM,QN)                                                       \
  __builtin_amdgcn_s_setprio(1);                                               \
  _Pragma("unroll")                                                            \
  for (int ks=0;ks<2;ks++)                                                     \
    _Pragma("unroll")                                                          \
    for (int Mf=0;Mf<4;Mf++)                                                   \
      _Pragma("unroll")                                                        \
      for (int Nf=0;Nf<2;Nf++)                                                 \
        acc[(QM)*4+Mf][(QN)*2+Nf] = __builtin_amdgcn_mfma_f32_16x16x32_bf16(   \
            af[Mf][ks], bf[Nf][ks], acc[(QM)*4+Mf][(QN)*2+Nf], 0, 0, 0);       \
  __builtin_amdgcn_s_setprio(0);

#define BAR()  __builtin_amdgcn_s_barrier()
#define LGKM0() asm volatile("s_waitcnt lgkmcnt(0)" ::: "memory")

  // prologue: stage K-tile 0 fully; force idx0,idx1 landed (idx2,idx3 afloat)
  stageHT(0,0); stageHT(0,1); stageHT(0,2); stageHT(0,3);
  asm volatile("s_waitcnt vmcnt(4)" ::: "memory");
  BAR();

  for (int t=0; t<NT; ++t){
    bool pf = (t+1 < NT);
    // ---- P0 (qm0,qn0): guarantee (t,idx2) for P1's reads ----
    readA(t,0); readB(t,0);
    if (pf){ stageHT(t+1,0); asm volatile("s_waitcnt vmcnt(4)" ::: "memory"); }
    else   {                 asm volatile("s_waitcnt vmcnt(2)" ::: "memory"); }
    BAR(); LGKM0();
    MMA_PHASE(0,0);
    BAR();
    // ---- P1 (qm1,qn0): guarantee (t,idx3) for P2's reads ----
    readA(t,1);
    if (pf){ stageHT(t+1,1); asm volatile("s_waitcnt vmcnt(4)" ::: "memory"); }
    else   {                 asm volatile("s_waitcnt vmcnt(0)" ::: "memory"); }
    BAR(); LGKM0();
    MMA_PHASE(1,0);
    BAR();
    // ---- P2 (qm1,qn1): no wait needed ----
    readB(t,1);
    if (pf) stageHT(t+1,2);
    BAR(); LGKM0();
    MMA_PHASE(1,1);
    BAR();
    // ---- P3 (qm0,qn1): guarantee (t+1,idx0),(t+1,idx1) for next P0 ----
    readA(t,0);
    if (pf){ stageHT(t+1,3); asm volatile("s_waitcnt vmcnt(4)" ::: "memory"); }
    BAR(); LGKM0();
    MMA_PHASE(0,1);
    BAR();
  }

  // epilogue: C/D layout col = lane&15, row = (lane>>4)*4 + reg
  // gm = m0 + qm*128 + wr*64 + Mf*16 + lq*4 + rg; gn = n0 + qn*128 + wc*32 + Nf*16 + lrow
  #pragma unroll
  for (int Mi=0;Mi<8;Mi++){
    int qm = Mi>>2, Mf = Mi&3;
    #pragma unroll
    for (int Nj=0;Nj<4;Nj++){
      int qn = Nj>>1, Nf = Nj&1;
      #pragma unroll
      for (int rg=0;rg<4;rg++){
        int gm = m0 + qm*128 + wr*64 + Mf*16 + lq*4 + rg;
        int gn = n0 + qn*128 + wc*32 + Nf*16 + lrow;
        float v = acc[Mi][Nj][rg];
        if (MODE==0){
          v = fmaxf(v, 0.f) * rw[gm*E_NUM + z];
          outInter[(size_t)gm*(E_NUM*I_DIM) + (size_t)z*I_DIM + gn] = f2bf(v);
        } else {
          atomicAdd(&outAdd[(size_t)gm*H_DIM + gn], v);
        }
      }
    }
  }
#undef MMA_PHASE
#undef BAR
#undef LGKM0
}

extern "C" void kernel_launch(void* const* d_in, const int* in_sizes, int n_in,
                              void* d_out, int out_size, void* d_ws, size_t ws_size,
                              hipStream_t stream)
{
  const float* x   = (const float*)d_in[0];
  const float* rww = (const float*)d_in[1];
  const float* rwb = (const float*)d_in[2];
  const float* w1  = (const float*)d_in[3];  // (E, H, I)
  const float* w2  = (const float*)d_in[4];  // (E, I, H)
  float* out = (float*)d_out;

  char* ws = (char*)d_ws;
  float*          rwout = (float*)(ws);                         // 32 KB
  unsigned short* xb    = (unsigned short*)(ws + (1u<<16));     // 2 MB  @64KB
  unsigned short* inter = (unsigned short*)(ws + (4ull<<20));   // 64 MB @4MB
  unsigned short* wt    = (unsigned short*)(ws + (68ull<<20));  // 64 MB @68MB
  const size_t needed = 132ull<<20;

  zero_kernel<<<2048, 256, 0, stream>>>((float4*)out, out_size/4);
  if (ws_size < needed) return;

  void* k0 = (void*)gemm8p<0>;
  void* k1 = (void*)gemm8p<1>;
  hipFuncSetAttribute(k0, hipFuncAttributeMaxDynamicSharedMemorySize, 131072);
  hipFuncSetAttribute(k1, hipFuncAttributeMaxDynamicSharedMemorySize, 131072);

  router_kernel<<<CAP, 256, 0, stream>>>(x, rww, rwb, xb, rwout);

  // W1 (E,H,I) -> W1^T per expert (I x H) bf16
  transpose_cvt64<<<dim3(I_DIM/64, H_DIM/64, E_NUM), 256, 0, stream>>>(
      w1, wt, H_DIM, I_DIM, (long)H_DIM*I_DIM, (long)I_DIM*H_DIM);

  // GEMM1: inter[c, e*I+n] = bf16( relu( xb @ W1_e^T ) * rw[c,e] )
  // grid 512 = (4 mtiles x 16 ntiles) x 8 experts; K=1024 -> NT=16
  gemm8p<0><<<512, 512, 131072, stream>>>(
      xb, H_DIM, 0L,
      wt, H_DIM, (long)I_DIM*H_DIM,
      16, 64, rwout, inter, nullptr);

  // W2 flat (E*I x H) -> W2^T (H x E*I) bf16
  transpose_cvt64<<<dim3(H_DIM/64, (E_NUM*I_DIM)/64, 1), 256, 0, stream>>>(
      w2, wt, E_NUM*I_DIM, H_DIM, 0L, 0L);

  // GEMM2: out[c,h] += inter[c,:] @ W2^T[h,:]; split-K z=16 slices of 2048 -> NT=32
  // grid 256 = (4 mtiles x 4 ntiles) x 16 z
  gemm8p<1><<<256, 512, 131072, stream>>>(
      inter, E_NUM*I_DIM, 2048L,
      wt,    E_NUM*I_DIM, 2048L,
      32, 16, nullptr, nullptr, out);
}

// Round 10
// 252.639 us; speedup vs baseline: 5.6037x; 1.1119x over previous
//
#include <hip/hip_runtime.h>
#include <stdint.h>

#define H_DIM 1024
#define I_DIM 4096
#define E_NUM 8
#define CAP   1024

typedef __attribute__((ext_vector_type(8))) short bf16x8;
typedef __attribute__((ext_vector_type(4))) float f32x4;

#define AS1 __attribute__((address_space(1)))
#define AS3 __attribute__((address_space(3)))

__device__ __forceinline__ unsigned short f2bf(float f){
  union { float f; uint32_t u; } v; v.f = f;
  uint32_t u = v.u;
  uint32_t r = (u + 0x7FFFu + ((u >> 16) & 1u)) >> 16;
  return (unsigned short)r;
}

// ---------------- zero output ----------------
__global__ void zero_kernel(float4* __restrict__ p, int n4){
  int i = blockIdx.x*blockDim.x + threadIdx.x;
  int stride = gridDim.x*blockDim.x;
  float4 z; z.x=0.f; z.y=0.f; z.z=0.f; z.w=0.f;
  for (; i < n4; i += stride) p[i] = z;
}

// ---------------- router softmax + x -> bf16 (first CAP tokens) ----------------
__global__ __launch_bounds__(256) void router_kernel(
    const float* __restrict__ x, const float* __restrict__ rw_w,
    const float* __restrict__ rb, unsigned short* __restrict__ xb,
    float* __restrict__ rwout)
{
  int c = blockIdx.x;
  int t = threadIdx.x;
  float acc[E_NUM];
  #pragma unroll
  for (int e=0;e<E_NUM;e++) acc[e]=0.f;
  const float* xr = x + (size_t)c*H_DIM;
  for (int h=t; h<H_DIM; h+=256){
    float xv = xr[h];
    xb[(size_t)c*H_DIM + h] = f2bf(xv);
    #pragma unroll
    for (int e=0;e<E_NUM;e++) acc[e] += xv * rw_w[e*H_DIM + h];
  }
  __shared__ float part[256][E_NUM];
  #pragma unroll
  for (int e=0;e<E_NUM;e++) part[t][e]=acc[e];
  __syncthreads();
  for (int s=128; s>0; s>>=1){
    if (t<s){
      #pragma unroll
      for (int e=0;e<E_NUM;e++) part[t][e]+=part[t+s][e];
    }
    __syncthreads();
  }
  if (t==0){
    float l[E_NUM], mx=-1e30f;
    #pragma unroll
    for (int e=0;e<E_NUM;e++){ l[e]=part[0][e]+rb[e]; mx=fmaxf(mx,l[e]); }
    float s=0.f;
    #pragma unroll
    for (int e=0;e<E_NUM;e++){ l[e]=expf(l[e]-mx); s+=l[e]; }
    float inv = 1.f/s;
    #pragma unroll
    for (int e=0;e<E_NUM;e++) rwout[c*E_NUM+e] = l[e]*inv;
  }
}

// ------- fp32 -> bf16 transpose, 64x64 tile, float4 loads / ushort4 stores -------
__global__ __launch_bounds__(256) void transpose_cvt64(
    const float* __restrict__ src, unsigned short* __restrict__ dst,
    int R, int C, long srcZ, long dstZ)
{
  src += (size_t)blockIdx.z * srcZ;
  dst += (size_t)blockIdx.z * dstZ;
  __shared__ float tile[64][65];
  int c0 = blockIdx.x*64, r0 = blockIdx.y*64;
  int t  = threadIdx.x;
  int tx = t & 15, ty = t >> 4;
  #pragma unroll
  for (int p=0;p<4;p++){
    int r = ty + p*16;
    float4 v = *(const float4*)(src + (size_t)(r0+r)*C + c0 + tx*4);
    tile[r][tx*4+0]=v.x; tile[r][tx*4+1]=v.y; tile[r][tx*4+2]=v.z; tile[r][tx*4+3]=v.w;
  }
  __syncthreads();
  #pragma unroll
  for (int p=0;p<4;p++){
    int c = ty + p*16;
    ushort4 o;
    o.x = f2bf(tile[tx*4+0][c]);
    o.y = f2bf(tile[tx*4+1][c]);
    o.z = f2bf(tile[tx*4+2][c]);
    o.w = f2bf(tile[tx*4+3][c]);
    *(ushort4*)(dst + (size_t)(c0+c)*R + r0 + tx*4) = o;
  }
}

// ---- 128x256 bf16 GEMM, B N-major, BK=64, SINGLE 48KB LDS buffer ----
// 8 waves (2M x 4N), wave out 64x64 (acc = 64 VGPR), launch_bounds(512,4)
// -> 2 resident blocks/CU (4 waves/SIMD): cross-block wave overlap covers
// the __syncthreads vmcnt drains (m114/m97 mechanism). Plain 2-barrier loop.
// Read swizzle = R2's measured-zero-conflict pattern: 128B rows,
// slot = (kk*4+lq) ^ (lrow&7); staging source pre-swizzled, LDS dest linear.
// MODE 0: relu*rw -> bf16 inter.  MODE 1: atomicAdd fp32.
template<int MODE>
__global__ __launch_bounds__(512, 4) void gemm_s(
    const unsigned short* __restrict__ A, int lda, long aZ,
    const unsigned short* __restrict__ B, int ldb, long bZ,
    int NS, int tilesPerZ,
    const float* __restrict__ rw,
    unsigned short* __restrict__ outInter,
    float* __restrict__ outAdd)
{
  __shared__ unsigned short As[128*64];   // 16 KB
  __shared__ unsigned short Bs[256*64];   // 32 KB

  // T1: XCD-aware swizzle (gridDim.x % 8 == 0); m-tiles fastest in chunk.
  // GEMM1: one expert per XCD -> W1_e panel lives in that XCD's L2.
  int nwg = gridDim.x;
  int id  = blockIdx.x;
  int swz = (id & 7)*(nwg >> 3) + (id >> 3);
  int z   = swz / tilesPerZ;
  int rr_ = swz - z*tilesPerZ;
  int mt  = rr_ & 7, nt = rr_ >> 3;
  int m0  = mt*128, n0 = nt*256;

  const unsigned short* Ab = A + (size_t)z*aZ + (size_t)m0*lda;
  const unsigned short* Bb = B + (size_t)z*bZ + (size_t)n0*ldb;

  int tid  = threadIdx.x;
  int w    = tid >> 6, l = tid & 63;
  int wr   = w >> 2,  wc = w & 3;       // wave grid 2M x 4N, wave out 64x64
  int lrow = l & 15,  lq = l >> 4;
  int r7   = lrow & 7;

  // staging: lane covers dest row base+(l>>3), slot l&7 (linear);
  // source elem offset = ((l&7) ^ ((l>>3)&7))*8  [R2 involution]
  int srow = l >> 3;
  int sg   = ((l & 7) ^ ((l >> 3) & 7)) * 8;

  f32x4 acc[4][4];
  #pragma unroll
  for (int i=0;i<4;i++)
    #pragma unroll
    for (int j=0;j<4;j++)
      acc[i][j] = (f32x4){0.f,0.f,0.f,0.f};

  for (int s=0; s<NS; ++s){
    int kt = s*64;
    // A: 2 instrs/wave, rows [w*16, w*16+16)
    #pragma unroll
    for (int i=0;i<2;i++){
      int rbase = w*16 + i*8;
      __builtin_amdgcn_global_load_lds(
        (const AS1 void*)(Ab + (size_t)(rbase + srow)*lda + kt + sg),
        (AS3 void*)((char*)As + rbase*128), 16, 0, 0);
    }
    // B: 4 instrs/wave, rows [w*32, w*32+32)
    #pragma unroll
    for (int i=0;i<4;i++){
      int rbase = w*32 + i*8;
      __builtin_amdgcn_global_load_lds(
        (const AS1 void*)(Bb + (size_t)(rbase + srow)*ldb + kt + sg),
        (AS3 void*)((char*)Bs + rbase*128), 16, 0, 0);
    }
    __syncthreads();   // drains vmcnt -> all waves' tiles in LDS

    #pragma unroll
    for (int kk=0;kk<2;kk++){
      bf16x8 af[4], bfr[4];
      int slot = ((kk*4 + lq) ^ r7) << 4;
      #pragma unroll
      for (int f=0;f<4;f++)
        af[f]  = *(const bf16x8*)((const char*)As + (wr*64 + f*16 + lrow)*128 + slot);
      #pragma unroll
      for (int f=0;f<4;f++)
        bfr[f] = *(const bf16x8*)((const char*)Bs + (wc*64 + f*16 + lrow)*128 + slot);
      __builtin_amdgcn_s_setprio(1);
      #pragma unroll
      for (int fm=0;fm<4;fm++)
        #pragma unroll
        for (int fn=0;fn<4;fn++)
          acc[fm][fn] = __builtin_amdgcn_mfma_f32_16x16x32_bf16(af[fm], bfr[fn], acc[fm][fn], 0, 0, 0);
      __builtin_amdgcn_s_setprio(0);
    }

    __syncthreads();   // protect LDS before next stage
  }

  // epilogue: C/D layout col = lane&15, row = (lane>>4)*4 + reg
  #pragma unroll
  for (int fm=0;fm<4;fm++){
    #pragma unroll
    for (int fn=0;fn<4;fn++){
      #pragma unroll
      for (int rg=0;rg<4;rg++){
        int gm = m0 + wr*64 + fm*16 + lq*4 + rg;
        int gn = n0 + wc*64 + fn*16 + lrow;
        float v = acc[fm][fn][rg];
        if (MODE==0){
          v = fmaxf(v, 0.f) * rw[gm*E_NUM + z];
          outInter[(size_t)gm*(E_NUM*I_DIM) + (size_t)z*I_DIM + gn] = f2bf(v);
        } else {
          atomicAdd(&outAdd[(size_t)gm*H_DIM + gn], v);
        }
      }
    }
  }
}

extern "C" void kernel_launch(void* const* d_in, const int* in_sizes, int n_in,
                              void* d_out, int out_size, void* d_ws, size_t ws_size,
                              hipStream_t stream)
{
  const float* x   = (const float*)d_in[0];
  const float* rww = (const float*)d_in[1];
  const float* rwb = (const float*)d_in[2];
  const float* w1  = (const float*)d_in[3];  // (E, H, I)
  const float* w2  = (const float*)d_in[4];  // (E, I, H)
  float* out = (float*)d_out;

  char* ws = (char*)d_ws;
  float*          rwout = (float*)(ws);                         // 32 KB
  unsigned short* xb    = (unsigned short*)(ws + (1u<<16));     // 2 MB  @64KB
  unsigned short* inter = (unsigned short*)(ws + (4ull<<20));   // 64 MB @4MB
  unsigned short* wt    = (unsigned short*)(ws + (68ull<<20));  // 64 MB @68MB
  const size_t needed = 132ull<<20;

  zero_kernel<<<2048, 256, 0, stream>>>((float4*)out, out_size/4);
  if (ws_size < needed) return;

  router_kernel<<<CAP, 256, 0, stream>>>(x, rww, rwb, xb, rwout);

  // W1 (E,H,I) -> W1^T per expert (I x H) bf16
  transpose_cvt64<<<dim3(I_DIM/64, H_DIM/64, E_NUM), 256, 0, stream>>>(
      w1, wt, H_DIM, I_DIM, (long)H_DIM*I_DIM, (long)I_DIM*H_DIM);

  // GEMM1: inter[c, e*I+n] = bf16( relu( xb @ W1_e^T ) * rw[c,e] )
  // grid 1024 = (8 mtiles x 16 ntiles) x 8 experts; K=1024 -> NS=16
  gemm_s<0><<<1024, 512, 0, stream>>>(
      xb, H_DIM, 0L,
      wt, H_DIM, (long)I_DIM*H_DIM,
      16, 128, rwout, inter, nullptr);

  // W2 flat (E*I x H) -> W2^T (H x E*I) bf16
  transpose_cvt64<<<dim3(H_DIM/64, (E_NUM*I_DIM)/64, 1), 256, 0, stream>>>(
      w2, wt, E_NUM*I_DIM, H_DIM, 0L, 0L);

  // GEMM2: out[c,h] += inter[c,:] @ W2^T[h,:]; split-K z=16 slices of 2048 -> NS=32
  // grid 512 = (8 mtiles x 4 ntiles) x 16 z
  gemm_s<1><<<512, 512, 0, stream>>>(
      inter, E_NUM*I_DIM, 2048L,
      wt,    E_NUM*I_DIM, 2048L,
      32, 32, nullptr, nullptr, out);
}

// Round 11
// 247.446 us; speedup vs baseline: 5.7213x; 1.0210x over previous
//
#include <hip/hip_runtime.h>
#include <stdint.h>

#define H_DIM 1024
#define I_DIM 4096
#define E_NUM 8
#define CAP   1024

typedef __attribute__((ext_vector_type(8))) short bf16x8;
typedef __attribute__((ext_vector_type(4))) float f32x4;

#define AS1 __attribute__((address_space(1)))
#define AS3 __attribute__((address_space(3)))

__device__ __forceinline__ unsigned short f2bf(float f){
  union { float f; uint32_t u; } v; v.f = f;
  uint32_t u = v.u;
  uint32_t r = (u + 0x7FFFu + ((u >> 16) & 1u)) >> 16;
  return (unsigned short)r;
}

// ---- fused prep: [0,1024) zero out | [1024,2048) router | [2048,10240) W1^T ----
// All three parts write disjoint buffers; no cross-part ordering needed.
__global__ __launch_bounds__(256) void prep_kernel(
    const float* __restrict__ x, const float* __restrict__ rw_w,
    const float* __restrict__ rb, const float* __restrict__ w1,
    float* __restrict__ out, int n4,
    unsigned short* __restrict__ xb, float* __restrict__ rwout,
    unsigned short* __restrict__ wt)
{
  __shared__ float smem[64][65];   // transpose tile; router uses a slice
  int bid = blockIdx.x;
  int t   = threadIdx.x;

  if (bid < 1024){
    // ---- zero out (32 MB) ----
    float4 z; z.x=0.f; z.y=0.f; z.z=0.f; z.w=0.f;
    float4* p = (float4*)out;
    for (int i = bid*256 + t; i < n4; i += 1024*256) p[i] = z;
    return;
  }
  if (bid < 2048){
    // ---- router softmax + x -> bf16 (one token per block) ----
    int c = bid - 1024;
    const float* xr = x + (size_t)c*H_DIM;
    float4 xv = *(const float4*)(xr + t*4);
    ushort4 xo;
    xo.x = f2bf(xv.x); xo.y = f2bf(xv.y); xo.z = f2bf(xv.z); xo.w = f2bf(xv.w);
    *(ushort4*)(xb + (size_t)c*H_DIM + t*4) = xo;
    float acc[E_NUM];
    #pragma unroll
    for (int e=0;e<E_NUM;e++){
      float4 wv = *(const float4*)(rw_w + e*H_DIM + t*4);
      acc[e] = xv.x*wv.x + xv.y*wv.y + xv.z*wv.z + xv.w*wv.w;
    }
    float (*part)[E_NUM] = (float (*)[E_NUM])smem;   // 256*8*4 = 8 KB
    #pragma unroll
    for (int e=0;e<E_NUM;e++) part[t][e]=acc[e];
    __syncthreads();
    for (int s=128; s>0; s>>=1){
      if (t<s){
        #pragma unroll
        for (int e=0;e<E_NUM;e++) part[t][e]+=part[t+s][e];
      }
      __syncthreads();
    }
    if (t==0){
      float l[E_NUM], mx=-1e30f;
      #pragma unroll
      for (int e=0;e<E_NUM;e++){ l[e]=part[0][e]+rb[e]; mx=fmaxf(mx,l[e]); }
      float s=0.f;
      #pragma unroll
      for (int e=0;e<E_NUM;e++){ l[e]=expf(l[e]-mx); s+=l[e]; }
      float inv = 1.f/s;
      #pragma unroll
      for (int e=0;e<E_NUM;e++) rwout[c*E_NUM+e] = l[e]*inv;
    }
    return;
  }
  // ---- W1 (E,H,I) -> W1^T per expert (I x H) bf16, 64x64 tiles ----
  int idx = bid - 2048;                 // e*1024 + by*64 + bx
  int e   = idx >> 10;
  int rem = idx & 1023;
  int by  = rem >> 6, bx = rem & 63;
  const float* src = w1 + (size_t)e*H_DIM*I_DIM;
  unsigned short* dst = wt + (size_t)e*I_DIM*H_DIM;
  int c0 = bx*64, r0 = by*64;
  int tx = t & 15, ty = t >> 4;
  #pragma unroll
  for (int p=0;p<4;p++){
    int r = ty + p*16;
    float4 v = *(const float4*)(src + (size_t)(r0+r)*I_DIM + c0 + tx*4);
    smem[r][tx*4+0]=v.x; smem[r][tx*4+1]=v.y; smem[r][tx*4+2]=v.z; smem[r][tx*4+3]=v.w;
  }
  __syncthreads();
  #pragma unroll
  for (int p=0;p<4;p++){
    int c = ty + p*16;
    ushort4 o;
    o.x = f2bf(smem[tx*4+0][c]);
    o.y = f2bf(smem[tx*4+1][c]);
    o.z = f2bf(smem[tx*4+2][c]);
    o.w = f2bf(smem[tx*4+3][c]);
    *(ushort4*)(dst + (size_t)(c0+c)*H_DIM + r0 + tx*4) = o;
  }
}

// ------- fp32 -> bf16 transpose, 64x64 tile, float4 loads / ushort4 stores -------
__global__ __launch_bounds__(256) void transpose_cvt64(
    const float* __restrict__ src, unsigned short* __restrict__ dst,
    int R, int C, long srcZ, long dstZ)
{
  src += (size_t)blockIdx.z * srcZ;
  dst += (size_t)blockIdx.z * dstZ;
  __shared__ float tile[64][65];
  int c0 = blockIdx.x*64, r0 = blockIdx.y*64;
  int t  = threadIdx.x;
  int tx = t & 15, ty = t >> 4;
  #pragma unroll
  for (int p=0;p<4;p++){
    int r = ty + p*16;
    float4 v = *(const float4*)(src + (size_t)(r0+r)*C + c0 + tx*4);
    tile[r][tx*4+0]=v.x; tile[r][tx*4+1]=v.y; tile[r][tx*4+2]=v.z; tile[r][tx*4+3]=v.w;
  }
  __syncthreads();
  #pragma unroll
  for (int p=0;p<4;p++){
    int c = ty + p*16;
    ushort4 o;
    o.x = f2bf(tile[tx*4+0][c]);
    o.y = f2bf(tile[tx*4+1][c]);
    o.z = f2bf(tile[tx*4+2][c]);
    o.w = f2bf(tile[tx*4+3][c]);
    *(ushort4*)(dst + (size_t)(c0+c)*R + r0 + tx*4) = o;
  }
}

// ---- 128x256 bf16 GEMM, B N-major, BK=64, SINGLE 48KB LDS buffer ----
// (byte-identical to R10's gemm_s: 8 waves 2Mx4N, wave out 64x64, 2 blocks/CU,
// plain 2-barrier loop, R2-proven zero-conflict swizzle, T1 XCD swizzle.)
// MODE 0: relu*rw -> bf16 inter.  MODE 1: atomicAdd fp32.
template<int MODE>
__global__ __launch_bounds__(512, 4) void gemm_s(
    const unsigned short* __restrict__ A, int lda, long aZ,
    const unsigned short* __restrict__ B, int ldb, long bZ,
    int NS, int tilesPerZ,
    const float* __restrict__ rw,
    unsigned short* __restrict__ outInter,
    float* __restrict__ outAdd)
{
  __shared__ unsigned short As[128*64];   // 16 KB
  __shared__ unsigned short Bs[256*64];   // 32 KB

  int nwg = gridDim.x;
  int id  = blockIdx.x;
  int swz = (id & 7)*(nwg >> 3) + (id >> 3);
  int z   = swz / tilesPerZ;
  int rr_ = swz - z*tilesPerZ;
  int mt  = rr_ & 7, nt = rr_ >> 3;
  int m0  = mt*128, n0 = nt*256;

  const unsigned short* Ab = A + (size_t)z*aZ + (size_t)m0*lda;
  const unsigned short* Bb = B + (size_t)z*bZ + (size_t)n0*ldb;

  int tid  = threadIdx.x;
  int w    = tid >> 6, l = tid & 63;
  int wr   = w >> 2,  wc = w & 3;       // wave grid 2M x 4N, wave out 64x64
  int lrow = l & 15,  lq = l >> 4;
  int r7   = lrow & 7;

  int srow = l >> 3;
  int sg   = ((l & 7) ^ ((l >> 3) & 7)) * 8;

  f32x4 acc[4][4];
  #pragma unroll
  for (int i=0;i<4;i++)
    #pragma unroll
    for (int j=0;j<4;j++)
      acc[i][j] = (f32x4){0.f,0.f,0.f,0.f};

  for (int s=0; s<NS; ++s){
    int kt = s*64;
    #pragma unroll
    for (int i=0;i<2;i++){
      int rbase = w*16 + i*8;
      __builtin_amdgcn_global_load_lds(
        (const AS1 void*)(Ab + (size_t)(rbase + srow)*lda + kt + sg),
        (AS3 void*)((char*)As + rbase*128), 16, 0, 0);
    }
    #pragma unroll
    for (int i=0;i<4;i++){
      int rbase = w*32 + i*8;
      __builtin_amdgcn_global_load_lds(
        (const AS1 void*)(Bb + (size_t)(rbase + srow)*ldb + kt + sg),
        (AS3 void*)((char*)Bs + rbase*128), 16, 0, 0);
    }
    __syncthreads();

    #pragma unroll
    for (int kk=0;kk<2;kk++){
      bf16x8 af[4], bfr[4];
      int slot = ((kk*4 + lq) ^ r7) << 4;
      #pragma unroll
      for (int f=0;f<4;f++)
        af[f]  = *(const bf16x8*)((const char*)As + (wr*64 + f*16 + lrow)*128 + slot);
      #pragma unroll
      for (int f=0;f<4;f++)
        bfr[f] = *(const bf16x8*)((const char*)Bs + (wc*64 + f*16 + lrow)*128 + slot);
      __builtin_amdgcn_s_setprio(1);
      #pragma unroll
      for (int fm=0;fm<4;fm++)
        #pragma unroll
        for (int fn=0;fn<4;fn++)
          acc[fm][fn] = __builtin_amdgcn_mfma_f32_16x16x32_bf16(af[fm], bfr[fn], acc[fm][fn], 0, 0, 0);
      __builtin_amdgcn_s_setprio(0);
    }

    __syncthreads();
  }

  #pragma unroll
  for (int fm=0;fm<4;fm++){
    #pragma unroll
    for (int fn=0;fn<4;fn++){
      #pragma unroll
      for (int rg=0;rg<4;rg++){
        int gm = m0 + wr*64 + fm*16 + lq*4 + rg;
        int gn = n0 + wc*64 + fn*16 + lrow;
        float v = acc[fm][fn][rg];
        if (MODE==0){
          v = fmaxf(v, 0.f) * rw[gm*E_NUM + z];
          outInter[(size_t)gm*(E_NUM*I_DIM) + (size_t)z*I_DIM + gn] = f2bf(v);
        } else {
          atomicAdd(&outAdd[(size_t)gm*H_DIM + gn], v);
        }
      }
    }
  }
}

extern "C" void kernel_launch(void* const* d_in, const int* in_sizes, int n_in,
                              void* d_out, int out_size, void* d_ws, size_t ws_size,
                              hipStream_t stream)
{
  const float* x   = (const float*)d_in[0];
  const float* rww = (const float*)d_in[1];
  const float* rwb = (const float*)d_in[2];
  const float* w1  = (const float*)d_in[3];  // (E, H, I)
  const float* w2  = (const float*)d_in[4];  // (E, I, H)
  float* out = (float*)d_out;

  char* ws = (char*)d_ws;
  float*          rwout = (float*)(ws);                         // 32 KB
  unsigned short* xb    = (unsigned short*)(ws + (1u<<16));     // 2 MB  @64KB
  unsigned short* inter = (unsigned short*)(ws + (4ull<<20));   // 64 MB @4MB
  unsigned short* wt    = (unsigned short*)(ws + (68ull<<20));  // 64 MB @68MB
  const size_t needed = 132ull<<20;

  if (ws_size < needed){
    // fallback: zero output only (signature: exact zeros)
    prep_kernel<<<1024, 256, 0, stream>>>(x, rww, rwb, w1, out, out_size/4,
                                          xb, rwout, wt);
    return;
  }

  // prep: zero(out) | router(xb,rwout) | W1^T(wt) in one dispatch
  prep_kernel<<<10240, 256, 0, stream>>>(x, rww, rwb, w1, out, out_size/4,
                                         xb, rwout, wt);

  // GEMM1: inter[c, e*I+n] = bf16( relu( xb @ W1_e^T ) * rw[c,e] )
  // grid 1024 = (8 mtiles x 16 ntiles) x 8 experts; K=1024 -> NS=16
  gemm_s<0><<<1024, 512, 0, stream>>>(
      xb, H_DIM, 0L,
      wt, H_DIM, (long)I_DIM*H_DIM,
      16, 128, rwout, inter, nullptr);

  // W2 flat (E*I x H) -> W2^T (H x E*I) bf16  (reuses wt after GEMM1)
  transpose_cvt64<<<dim3(H_DIM/64, (E_NUM*I_DIM)/64, 1), 256, 0, stream>>>(
      w2, wt, E_NUM*I_DIM, H_DIM, 0L, 0L);

  // GEMM2: out[c,h] += inter[c,:] @ W2^T[h,:]; split-K z=16 slices of 2048 -> NS=32
  // grid 512 = (8 mtiles x 4 ntiles) x 16 z
  gemm_s<1><<<512, 512, 0, stream>>>(
      inter, E_NUM*I_DIM, 2048L,
      wt,    E_NUM*I_DIM, 2048L,
      32, 32, nullptr, nullptr, out);
}